// Round 1
// baseline (118.842 us; speedup 1.0000x reference)
//
#include <hip/hip_runtime.h>
#include <math.h>

#define NN 50000
#define FD 128
#define HDIM 256
#define NE 800000
#define NBR_CAP 512
#define M_CAP 8192
#define TT 7

// ws byte offsets
#define O_DEG      0         // NN floats (200000 B)
#define O_NBRCNT   200704    // int
#define O_NBRNODE  200712    // NBR_CAP ints
#define O_NBRW     202760    // NBR_CAP floats
#define O_MCNT     204808    // int
#define O_MS       204816    // M_CAP ints
#define O_MC1      237584    // M_CAP floats
#define O_MC2      270352    // M_CAP floats
#define O_A1X      303120    // 128 f
#define O_A2X      303632    // 128 f
#define O_A1H      304144    // 256 f
#define O_A2H      305168    // 256 f
#define O_GACC     310800    // 4*256 f
#define O_HBUF     314896    // 2*256 f (double buffered)
#define O_CBUF     316944    // 2*256 f
#define O_OBUF     318992    // 7 f
#define WS_ZERO_BYTES 327680

__device__ __forceinline__ float sigm(float v) { return 1.f / (1.f + expf(-v)); }
__device__ __forceinline__ float dis_of(float dg) {
    return dg > 0.f ? rsqrtf(fmaxf(dg, 1e-20f)) : 0.f;
}

// Pass 1 over edges: deg[src] += w (self-loops zeroed); collect in-neighbors of node 0.
__global__ void k_deg_nbr(const int* __restrict__ ei, const float* __restrict__ ew,
                          float* deg, int* nbrCnt, int* nbrNode, float* nbrW) {
    int e = blockIdx.x * blockDim.x + threadIdx.x;
    if (e >= NE) return;
    int s = ei[e], d = ei[NE + e];
    if (s == d) return;                 // w zeroed on self-loops
    float w = ew[e];
    atomicAdd(&deg[s], w);
    if (d == 0 && w != 0.f) {
        int slot = atomicAdd(nbrCnt, 1);
        if (slot < NBR_CAP) { nbrNode[slot] = s; nbrW[slot] = w; }
    }
}

// Pass 2 over edges: compute per-edge coefficients c1 (first-hop) and c2 (second-hop),
// compact matching edges into a list.
__global__ void k_match(const int* __restrict__ ei, const float* __restrict__ ew,
                        const float* __restrict__ deg,
                        const int* __restrict__ nbrCnt, const int* __restrict__ nbrNode,
                        const float* __restrict__ nbrW,
                        int* mCnt, int* mS, float* mC1, float* mC2) {
    __shared__ int sNode[NBR_CAP];
    __shared__ float sW[NBR_CAP];
    __shared__ int sCnt;
    if (threadIdx.x == 0) sCnt = min(*nbrCnt, NBR_CAP);
    __syncthreads();
    int cnt = sCnt;
    for (int i = threadIdx.x; i < cnt; i += blockDim.x) { sNode[i] = nbrNode[i]; sW[i] = nbrW[i]; }
    __syncthreads();

    int e = blockIdx.x * blockDim.x + threadIdx.x;
    if (e >= NE) return;
    int s = ei[e], d = ei[NE + e];
    if (s == d) return;
    float w = ew[e];
    if (w == 0.f) return;
    float dis0 = dis_of(deg[0]);
    float diss = dis_of(deg[s]);
    float disd = dis_of(deg[d]);
    float wn = diss * w * disd;                 // w_norm of this edge
    float c1 = (d == 0) ? wn : 0.f;             // contributes to T1[0]
    float Wd = 0.f;                              // raw weight-sum of edges d->0
    for (int i = 0; i < cnt; ++i) Wd += (sNode[i] == d) ? sW[i] : 0.f;
    float c2 = wn * (dis0 * disd * Wd);         // contributes to lhat(T1)[0]
    if (c1 != 0.f || c2 != 0.f) {
        int slot = atomicAdd(mCnt, 1);
        if (slot < M_CAP) { mS[slot] = s; mC1[slot] = c1; mC2[slot] = c2; }
    }
}

// Accumulate A1/A2 vectors over the compact matched-edge list.
__global__ void k_accum(const float* __restrict__ x, const float* __restrict__ h,
                        const int* __restrict__ mCnt, const int* __restrict__ mS,
                        const float* __restrict__ mC1, const float* __restrict__ mC2,
                        float* A1x, float* A2x, float* A1h, float* A2h) {
    int cnt = min(*mCnt, M_CAP);
    int tid = threadIdx.x;                      // 384 threads: 0..127 -> x feats, 128..383 -> h feats
    float a1 = 0.f, a2 = 0.f;
    for (int i = blockIdx.x; i < cnt; i += gridDim.x) {
        int s = mS[i];
        float c1 = mC1[i], c2 = mC2[i];
        float v = (tid < FD) ? x[(size_t)s * FD + tid] : h[(size_t)s * HDIM + (tid - FD)];
        a1 += c1 * v;
        a2 += c2 * v;
    }
    if (tid < FD) { atomicAdd(&A1x[tid], a1); atomicAdd(&A2x[tid], a2); }
    else { atomicAdd(&A1h[tid - FD], a1); atomicAdd(&A2h[tid - FD], a2); }
}

// GEMV: g[gate][o] = sum_k sum_f T_k[f] * theta[gate][k][f][o]  (x-part + h-part)
// 32 blocks = 4 gates x 8 chunks, 256 threads (one per output o).
__global__ void k_gemv(const float* __restrict__ x, const float* __restrict__ h,
                       const float* __restrict__ A1x, const float* __restrict__ A2x,
                       const float* __restrict__ A1h, const float* __restrict__ A2h,
                       const float* __restrict__ theta_x, const float* __restrict__ theta_h,
                       float* gacc) {
    __shared__ float tx[3 * FD];
    __shared__ float th[3 * HDIM];
    for (int i = threadIdx.x; i < FD; i += blockDim.x) {
        float x0 = x[i];                         // node 0 row of x
        tx[i] = x0;
        tx[FD + i] = -A1x[i];                    // T1 = -A1
        tx[2 * FD + i] = 2.f * A2x[i] - x0;      // T2 = 2*lhat(T1) - T0
    }
    for (int i = threadIdx.x; i < HDIM; i += blockDim.x) {
        float h0 = h[i];
        th[i] = h0;
        th[HDIM + i] = -A1h[i];
        th[2 * HDIM + i] = 2.f * A2h[i] - h0;
    }
    __syncthreads();
    int g = blockIdx.x >> 3, chunk = blockIdx.x & 7;
    int o = threadIdx.x;
    const int PX = 3 * FD;              // 384
    const int PTOT = PX + 3 * HDIM;     // 1152
    const int CH = PTOT / 8;            // 144
    float acc = 0.f;
    for (int p = chunk * CH; p < (chunk + 1) * CH; ++p) {
        float tval;
        const float* row;
        if (p < PX) { tval = tx[p]; row = theta_x + ((size_t)(g * PX + p)) * HDIM; }
        else { int q = p - PX; tval = th[q]; row = theta_h + ((size_t)(g * 3 * HDIM + q)) * HDIM; }
        acc += tval * row[o];
    }
    atomicAdd(&gacc[g * HDIM + o], acc);
}

// LSTM cell at node 0 -> h0, c0 into double-buffer slot 0.
__global__ void k_gates(const float* __restrict__ c, const float* __restrict__ gacc,
                        const float* __restrict__ bias_x, const float* __restrict__ bias_h,
                        const float* __restrict__ w_c, const float* __restrict__ b_gate,
                        float* hbuf, float* cbuf) {
    int o = threadIdx.x;
    float g0 = gacc[0 * HDIM + o] + bias_x[0 * HDIM + o] + bias_h[0 * HDIM + o];
    float g1 = gacc[1 * HDIM + o] + bias_x[1 * HDIM + o] + bias_h[1 * HDIM + o];
    float g2 = gacc[2 * HDIM + o] + bias_x[2 * HDIM + o] + bias_h[2 * HDIM + o];
    float g3 = gacc[3 * HDIM + o] + bias_x[3 * HDIM + o] + bias_h[3 * HDIM + o];
    float c0 = c[o];                             // node 0 row of c
    float I  = sigm(g0 + w_c[0 * HDIM + o] * c0 + b_gate[0 * HDIM + o]);
    float Fg = sigm(g1 + w_c[1 * HDIM + o] * c0 + b_gate[1 * HDIM + o]);
    float Cn = Fg * c0 + I * tanhf(g2 + b_gate[2 * HDIM + o]);
    float O  = sigm(g3 + w_c[2 * HDIM + o] * Cn + b_gate[3 * HDIM + o]);
    hbuf[o] = O * tanhf(Cn);
    cbuf[o] = Cn;
}

// One scan step. 32 blocks x 64 threads; block b owns outputs [b*8, b*8+8).
// Double-buffered h/c (read parity t&1, write parity (t+1)&1) -> no intra-launch race.
__global__ void k_step(int t, const float* __restrict__ x,
                       const float* __restrict__ w_ih, const float* __restrict__ w_hh,
                       const float* __restrict__ b_ih, const float* __restrict__ b_hh,
                       const float* __restrict__ w_out, const float* __restrict__ b_out,
                       float* hbuf, float* cbuf, float* obuf) {
    __shared__ float sh[HDIM];
    const float* hr = hbuf + (t & 1) * HDIM;
    float* hw = hbuf + ((t + 1) & 1) * HDIM;
    const float* cr = cbuf + (t & 1) * HDIM;
    float* cw = cbuf + ((t + 1) & 1) * HDIM;
    int lane = threadIdx.x;                      // 64
    *(float4*)&sh[lane * 4] = *(const float4*)&hr[lane * 4];
    __syncthreads();
    float inp = (t == 0) ? x[FD - 1] : (obuf[t - 1] + b_out[0]);
    int b = blockIdx.x;
    int lr = lane & 31;                          // row within block's 32 rows
    int half = lane >> 5;                        // split 256-dot in halves
    int strip = lr >> 3, lt = lr & 7;            // strip = gate, lt = local element
    int j = strip * HDIM + b * 8 + lt;           // global gate row (0..1023)
    const float* wrow = w_hh + (size_t)j * HDIM + half * 128;
    const float* shh = sh + half * 128;
    float acc = 0.f;
    #pragma unroll 8
    for (int d0 = 0; d0 < 128; d0 += 4) {
        float4 wv = *(const float4*)&wrow[d0];
        acc += shh[d0] * wv.x + shh[d0 + 1] * wv.y + shh[d0 + 2] * wv.z + shh[d0 + 3] * wv.w;
    }
    acc += __shfl_down(acc, 32);                 // lanes 0..31 now hold full dots
    float gate = acc + inp * w_ih[j] + b_ih[j] + b_hh[j];
    float iv = __shfl(gate, lt);
    float fv = __shfl(gate, 8 + lt);
    float gv = __shfl(gate, 16 + lt);
    float ov = __shfl(gate, 24 + lt);
    float part = 0.f;
    int tg = b * 8 + lt;
    if (lane < 8) {
        float cd = cr[tg];
        float cn = sigm(fv) * cd + sigm(iv) * tanhf(gv);
        float hn = sigm(ov) * tanhf(cn);
        cw[tg] = cn;
        hw[tg] = hn;
        part = hn * w_out[tg];
    }
    part += __shfl_down(part, 4);
    part += __shfl_down(part, 2);
    part += __shfl_down(part, 1);
    if (lane == 0) atomicAdd(&obuf[t], part);
}

__global__ void k_final(const float* __restrict__ obuf, const float* __restrict__ b_out,
                        float* __restrict__ out) {
    int t = threadIdx.x;
    if (t < TT) out[t] = obuf[t] + b_out[0];
}

extern "C" void kernel_launch(void* const* d_in, const int* in_sizes, int n_in,
                              void* d_out, int out_size, void* d_ws, size_t ws_size,
                              hipStream_t stream) {
    const float* x       = (const float*)d_in[0];
    const int*   ei      = (const int*)d_in[1];
    const float* ew      = (const float*)d_in[2];
    const float* h       = (const float*)d_in[3];
    const float* c       = (const float*)d_in[4];
    const float* theta_x = (const float*)d_in[5];
    const float* bias_x  = (const float*)d_in[6];
    const float* theta_h = (const float*)d_in[7];
    const float* bias_h  = (const float*)d_in[8];
    const float* w_c     = (const float*)d_in[9];
    const float* b_gate  = (const float*)d_in[10];
    const float* w_ih    = (const float*)d_in[11];
    const float* w_hh    = (const float*)d_in[12];
    const float* b_ih    = (const float*)d_in[13];
    const float* b_hh    = (const float*)d_in[14];
    const float* w_out   = (const float*)d_in[15];
    const float* b_out   = (const float*)d_in[16];
    float* out = (float*)d_out;
    char* ws = (char*)d_ws;

    float* deg    = (float*)(ws + O_DEG);
    int*   nbrCnt = (int*)(ws + O_NBRCNT);
    int*   nbrNode= (int*)(ws + O_NBRNODE);
    float* nbrW   = (float*)(ws + O_NBRW);
    int*   mCnt   = (int*)(ws + O_MCNT);
    int*   mS     = (int*)(ws + O_MS);
    float* mC1    = (float*)(ws + O_MC1);
    float* mC2    = (float*)(ws + O_MC2);
    float* A1x    = (float*)(ws + O_A1X);
    float* A2x    = (float*)(ws + O_A2X);
    float* A1h    = (float*)(ws + O_A1H);
    float* A2h    = (float*)(ws + O_A2H);
    float* gacc   = (float*)(ws + O_GACC);
    float* hbuf   = (float*)(ws + O_HBUF);
    float* cbuf   = (float*)(ws + O_CBUF);
    float* obuf   = (float*)(ws + O_OBUF);

    hipMemsetAsync(d_ws, 0, WS_ZERO_BYTES, stream);

    int eb = (NE + 255) / 256;
    k_deg_nbr<<<eb, 256, 0, stream>>>(ei, ew, deg, nbrCnt, nbrNode, nbrW);
    k_match<<<eb, 256, 0, stream>>>(ei, ew, deg, nbrCnt, nbrNode, nbrW, mCnt, mS, mC1, mC2);
    k_accum<<<32, 384, 0, stream>>>(x, h, mCnt, mS, mC1, mC2, A1x, A2x, A1h, A2h);
    k_gemv<<<32, 256, 0, stream>>>(x, h, A1x, A2x, A1h, A2h, theta_x, theta_h, gacc);
    k_gates<<<1, 256, 0, stream>>>(c, gacc, bias_x, bias_h, w_c, b_gate, hbuf, cbuf);
    for (int t = 0; t < TT; ++t)
        k_step<<<32, 64, 0, stream>>>(t, x, w_ih, w_hh, b_ih, b_hh, w_out, b_out, hbuf, cbuf, obuf);
    k_final<<<1, 64, 0, stream>>>(obuf, b_out, out);
}

// Round 2
// 94.866 us; speedup vs baseline: 1.2527x; 1.2527x over previous
//
#include <hip/hip_runtime.h>
#include <math.h>

#define NN 50000
#define FD 128
#define HDIM 256
#define NE 800000
#define NBR_CAP 512
#define M_CAP 8192
#define TT 7

// ws byte offsets
#define O_DEG      0         // NN floats (200000 B)
#define O_BITMAP   200704    // 1568 words (50176 bits)
#define O_NBRCNT   207104    // int
#define O_MCNT     207232    // int
#define O_NBRNODE  207360    // NBR_CAP ints
#define O_NBRW     209408    // NBR_CAP floats
#define O_MS       211456    // M_CAP ints
#define O_MD       244224    // M_CAP ints
#define O_MW       276992    // M_CAP floats
#define O_A1X      309760    // 128 f
#define O_A2X      310272    // 128 f
#define O_A1H      310784    // 256 f
#define O_A2H      311808    // 256 f
#define O_GACC     312832    // 4*256 f
#define O_HBUF     316928    // 2*256 f (16B aligned)
#define O_CBUF     318976    // 2*256 f
#define O_OBUF     321024    // 7 f
#define WS_ZERO_BYTES 321280

__device__ __forceinline__ float sigm(float v) { return 1.f / (1.f + expf(-v)); }
__device__ __forceinline__ float dis_of(float dg) {
    return dg > 0.f ? rsqrtf(fmaxf(dg, 1e-20f)) : 0.f;
}

// Pass 1: scan dst column (4 edges/thread), collect in-neighbors of node 0.
__global__ void k_nbr(const int* __restrict__ ei, const float* __restrict__ ew,
                      int* nbrCnt, int* nbrNode, float* nbrW) {
    int i = blockIdx.x * blockDim.x + threadIdx.x;
    int e0 = i * 4;
    if (e0 >= NE) return;
    int4 d4 = *(const int4*)&ei[NE + e0];
    float4 w4 = *(const float4*)&ew[e0];
    int dd[4] = {d4.x, d4.y, d4.z, d4.w};
    float wv[4] = {w4.x, w4.y, w4.z, w4.w};
    #pragma unroll
    for (int k = 0; k < 4; ++k) {
        if (dd[k] == 0 && wv[k] != 0.f) {
            int s = ei[e0 + k];
            if (s != 0) {                       // self-loop excluded
                int slot = atomicAdd(nbrCnt, 1);
                if (slot < NBR_CAP) { nbrNode[slot] = s; nbrW[slot] = wv[k]; }
            }
        }
    }
}

// Pass 2: match edges with d==0 or d in nbr(0); record (s,d,w); mark needed nodes in bitmap.
__global__ void k_match(const int* __restrict__ ei, const float* __restrict__ ew,
                        const int* __restrict__ nbrCnt, const int* __restrict__ nbrNode,
                        int* mCnt, int* mS, int* mD, float* mW, unsigned* bitmap) {
    __shared__ int sNode[NBR_CAP];
    __shared__ int sCnt;
    if (threadIdx.x == 0) sCnt = min(*nbrCnt, NBR_CAP);
    __syncthreads();
    int cnt = sCnt;
    for (int i = threadIdx.x; i < cnt; i += blockDim.x) sNode[i] = nbrNode[i];
    __syncthreads();
    if (blockIdx.x == 0 && threadIdx.x == 0) atomicOr(&bitmap[0], 1u);  // node 0 needed

    int i = blockIdx.x * blockDim.x + threadIdx.x;
    int e0 = i * 4;
    if (e0 >= NE) return;
    int4 s4 = *(const int4*)&ei[e0];
    int4 d4 = *(const int4*)&ei[NE + e0];
    float4 w4 = *(const float4*)&ew[e0];
    int ss[4] = {s4.x, s4.y, s4.z, s4.w};
    int dd[4] = {d4.x, d4.y, d4.z, d4.w};
    float wv[4] = {w4.x, w4.y, w4.z, w4.w};
    bool m[4];
    #pragma unroll
    for (int k = 0; k < 4; ++k) m[k] = (dd[k] == 0);
    for (int j = 0; j < cnt; ++j) {
        int nv = sNode[j];
        #pragma unroll
        for (int k = 0; k < 4; ++k) m[k] |= (dd[k] == nv);
    }
    #pragma unroll
    for (int k = 0; k < 4; ++k) {
        int s = ss[k], d = dd[k];
        float w = wv[k];
        if (s == d || w == 0.f || !m[k]) continue;
        int slot = atomicAdd(mCnt, 1);
        if (slot < M_CAP) { mS[slot] = s; mD[slot] = d; mW[slot] = w; }
        atomicOr(&bitmap[s >> 5], 1u << (s & 31));
        atomicOr(&bitmap[d >> 5], 1u << (d & 31));
    }
}

// Pass 3: deg[s] += w only for bitmap-marked srcs (~hundreds of atomics total).
__global__ void k_deg(const int* __restrict__ ei, const float* __restrict__ ew,
                      const unsigned* __restrict__ bitmap, float* deg) {
    int i = blockIdx.x * blockDim.x + threadIdx.x;
    int e0 = i * 4;
    if (e0 >= NE) return;
    int4 s4 = *(const int4*)&ei[e0];
    int4 d4 = *(const int4*)&ei[NE + e0];
    float4 w4 = *(const float4*)&ew[e0];
    int ss[4] = {s4.x, s4.y, s4.z, s4.w};
    int dd[4] = {d4.x, d4.y, d4.z, d4.w};
    float wv[4] = {w4.x, w4.y, w4.z, w4.w};
    #pragma unroll
    for (int k = 0; k < 4; ++k) {
        int s = ss[k];
        if (s == dd[k] || wv[k] == 0.f) continue;
        if (bitmap[s >> 5] & (1u << (s & 31)))   // 6.25 KB table: L1-resident
            atomicAdd(&deg[s], wv[k]);
    }
}

// Coefficients + accumulate A1/A2 over the compact matched-edge list.
__global__ void k_accum(const float* __restrict__ x, const float* __restrict__ h,
                        const float* __restrict__ deg,
                        const int* __restrict__ nbrCnt, const int* __restrict__ nbrNode,
                        const float* __restrict__ nbrW,
                        const int* __restrict__ mCnt, const int* __restrict__ mS,
                        const int* __restrict__ mD, const float* __restrict__ mW,
                        float* A1x, float* A2x, float* A1h, float* A2h) {
    __shared__ int sNode[NBR_CAP];
    __shared__ float sW[NBR_CAP];
    __shared__ int sCnt;
    if (threadIdx.x == 0) sCnt = min(*nbrCnt, NBR_CAP);
    __syncthreads();
    int ncnt = sCnt;
    for (int i = threadIdx.x; i < ncnt; i += blockDim.x) { sNode[i] = nbrNode[i]; sW[i] = nbrW[i]; }
    __syncthreads();

    int cnt = min(*mCnt, M_CAP);
    float dis0 = dis_of(deg[0]);
    int tid = threadIdx.x;                      // 0..127 -> x feats, 128..383 -> h feats
    float a1 = 0.f, a2 = 0.f;
    for (int i = blockIdx.x; i < cnt; i += gridDim.x) {
        int s = mS[i], d = mD[i];
        float w = mW[i];
        float diss = dis_of(deg[s]);            // wave-uniform address -> broadcast
        float disd = dis_of(deg[d]);
        float wn = diss * w * disd;
        float c1 = (d == 0) ? wn : 0.f;
        float Wd = 0.f;
        for (int j = 0; j < ncnt; ++j) Wd += (sNode[j] == d) ? sW[j] : 0.f;
        float c2 = wn * (dis0 * disd * Wd);
        float v = (tid < FD) ? x[(size_t)s * FD + tid] : h[(size_t)s * HDIM + (tid - FD)];
        a1 += c1 * v;
        a2 += c2 * v;
    }
    if (tid < FD) { atomicAdd(&A1x[tid], a1); atomicAdd(&A2x[tid], a2); }
    else { atomicAdd(&A1h[tid - FD], a1); atomicAdd(&A2h[tid - FD], a2); }
}

// GEMV: g[gate][o] = sum_k sum_f T_k[f] * theta[gate][k][f][o]  (x-part + h-part)
__global__ void k_gemv(const float* __restrict__ x, const float* __restrict__ h,
                       const float* __restrict__ A1x, const float* __restrict__ A2x,
                       const float* __restrict__ A1h, const float* __restrict__ A2h,
                       const float* __restrict__ theta_x, const float* __restrict__ theta_h,
                       float* gacc) {
    __shared__ float tx[3 * FD];
    __shared__ float th[3 * HDIM];
    for (int i = threadIdx.x; i < FD; i += blockDim.x) {
        float x0 = x[i];
        tx[i] = x0;
        tx[FD + i] = -A1x[i];                    // T1 = -A1
        tx[2 * FD + i] = 2.f * A2x[i] - x0;      // T2 = 2*lhat(T1) - T0
    }
    for (int i = threadIdx.x; i < HDIM; i += blockDim.x) {
        float h0 = h[i];
        th[i] = h0;
        th[HDIM + i] = -A1h[i];
        th[2 * HDIM + i] = 2.f * A2h[i] - h0;
    }
    __syncthreads();
    int g = blockIdx.x >> 3, chunk = blockIdx.x & 7;
    int o = threadIdx.x;
    const int PX = 3 * FD;
    const int PTOT = PX + 3 * HDIM;
    const int CH = PTOT / 8;
    float acc = 0.f;
    for (int p = chunk * CH; p < (chunk + 1) * CH; ++p) {
        float tval;
        const float* row;
        if (p < PX) { tval = tx[p]; row = theta_x + ((size_t)(g * PX + p)) * HDIM; }
        else { int q = p - PX; tval = th[q]; row = theta_h + ((size_t)(g * 3 * HDIM + q)) * HDIM; }
        acc += tval * row[o];
    }
    atomicAdd(&gacc[g * HDIM + o], acc);
}

__global__ void k_gates(const float* __restrict__ c, const float* __restrict__ gacc,
                        const float* __restrict__ bias_x, const float* __restrict__ bias_h,
                        const float* __restrict__ w_c, const float* __restrict__ b_gate,
                        float* hbuf, float* cbuf) {
    int o = threadIdx.x;
    float g0 = gacc[0 * HDIM + o] + bias_x[0 * HDIM + o] + bias_h[0 * HDIM + o];
    float g1 = gacc[1 * HDIM + o] + bias_x[1 * HDIM + o] + bias_h[1 * HDIM + o];
    float g2 = gacc[2 * HDIM + o] + bias_x[2 * HDIM + o] + bias_h[2 * HDIM + o];
    float g3 = gacc[3 * HDIM + o] + bias_x[3 * HDIM + o] + bias_h[3 * HDIM + o];
    float c0 = c[o];
    float I  = sigm(g0 + w_c[0 * HDIM + o] * c0 + b_gate[0 * HDIM + o]);
    float Fg = sigm(g1 + w_c[1 * HDIM + o] * c0 + b_gate[1 * HDIM + o]);
    float Cn = Fg * c0 + I * tanhf(g2 + b_gate[2 * HDIM + o]);
    float O  = sigm(g3 + w_c[2 * HDIM + o] * Cn + b_gate[3 * HDIM + o]);
    hbuf[o] = O * tanhf(Cn);
    cbuf[o] = Cn;
}

// One scan step. 32 blocks x 64 threads; block b owns outputs [b*8, b*8+8).
__global__ void k_step(int t, const float* __restrict__ x,
                       const float* __restrict__ w_ih, const float* __restrict__ w_hh,
                       const float* __restrict__ b_ih, const float* __restrict__ b_hh,
                       const float* __restrict__ w_out, const float* __restrict__ b_out,
                       float* hbuf, float* cbuf, float* obuf) {
    __shared__ float sh[HDIM];
    const float* hr = hbuf + (t & 1) * HDIM;
    float* hw = hbuf + ((t + 1) & 1) * HDIM;
    const float* cr = cbuf + (t & 1) * HDIM;
    float* cw = cbuf + ((t + 1) & 1) * HDIM;
    int lane = threadIdx.x;
    *(float4*)&sh[lane * 4] = *(const float4*)&hr[lane * 4];
    __syncthreads();
    float inp = (t == 0) ? x[FD - 1] : (obuf[t - 1] + b_out[0]);
    int b = blockIdx.x;
    int lr = lane & 31;
    int half = lane >> 5;
    int strip = lr >> 3, lt = lr & 7;
    int j = strip * HDIM + b * 8 + lt;
    const float* wrow = w_hh + (size_t)j * HDIM + half * 128;
    const float* shh = sh + half * 128;
    float acc = 0.f;
    #pragma unroll 8
    for (int d0 = 0; d0 < 128; d0 += 4) {
        float4 wv = *(const float4*)&wrow[d0];
        acc += shh[d0] * wv.x + shh[d0 + 1] * wv.y + shh[d0 + 2] * wv.z + shh[d0 + 3] * wv.w;
    }
    acc += __shfl_down(acc, 32);
    float gate = acc + inp * w_ih[j] + b_ih[j] + b_hh[j];
    float iv = __shfl(gate, lt);
    float fv = __shfl(gate, 8 + lt);
    float gv = __shfl(gate, 16 + lt);
    float ov = __shfl(gate, 24 + lt);
    float part = 0.f;
    int tg = b * 8 + lt;
    if (lane < 8) {
        float cd = cr[tg];
        float cn = sigm(fv) * cd + sigm(iv) * tanhf(gv);
        float hn = sigm(ov) * tanhf(cn);
        cw[tg] = cn;
        hw[tg] = hn;
        part = hn * w_out[tg];
    }
    part += __shfl_down(part, 4);
    part += __shfl_down(part, 2);
    part += __shfl_down(part, 1);
    if (lane == 0) atomicAdd(&obuf[t], part);
}

__global__ void k_final(const float* __restrict__ obuf, const float* __restrict__ b_out,
                        float* __restrict__ out) {
    int t = threadIdx.x;
    if (t < TT) out[t] = obuf[t] + b_out[0];
}

extern "C" void kernel_launch(void* const* d_in, const int* in_sizes, int n_in,
                              void* d_out, int out_size, void* d_ws, size_t ws_size,
                              hipStream_t stream) {
    const float* x       = (const float*)d_in[0];
    const int*   ei      = (const int*)d_in[1];
    const float* ew      = (const float*)d_in[2];
    const float* h       = (const float*)d_in[3];
    const float* c       = (const float*)d_in[4];
    const float* theta_x = (const float*)d_in[5];
    const float* bias_x  = (const float*)d_in[6];
    const float* theta_h = (const float*)d_in[7];
    const float* bias_h  = (const float*)d_in[8];
    const float* w_c     = (const float*)d_in[9];
    const float* b_gate  = (const float*)d_in[10];
    const float* w_ih    = (const float*)d_in[11];
    const float* w_hh    = (const float*)d_in[12];
    const float* b_ih    = (const float*)d_in[13];
    const float* b_hh    = (const float*)d_in[14];
    const float* w_out   = (const float*)d_in[15];
    const float* b_out   = (const float*)d_in[16];
    float* out = (float*)d_out;
    char* ws = (char*)d_ws;

    float*    deg    = (float*)(ws + O_DEG);
    unsigned* bitmap = (unsigned*)(ws + O_BITMAP);
    int*      nbrCnt = (int*)(ws + O_NBRCNT);
    int*      mCnt   = (int*)(ws + O_MCNT);
    int*      nbrNode= (int*)(ws + O_NBRNODE);
    float*    nbrW   = (float*)(ws + O_NBRW);
    int*      mS     = (int*)(ws + O_MS);
    int*      mD     = (int*)(ws + O_MD);
    float*    mW     = (float*)(ws + O_MW);
    float*    A1x    = (float*)(ws + O_A1X);
    float*    A2x    = (float*)(ws + O_A2X);
    float*    A1h    = (float*)(ws + O_A1H);
    float*    A2h    = (float*)(ws + O_A2H);
    float*    gacc   = (float*)(ws + O_GACC);
    float*    hbuf   = (float*)(ws + O_HBUF);
    float*    cbuf   = (float*)(ws + O_CBUF);
    float*    obuf   = (float*)(ws + O_OBUF);

    hipMemsetAsync(d_ws, 0, WS_ZERO_BYTES, stream);

    int eb4 = (NE / 4 + 255) / 256;
    k_nbr<<<eb4, 256, 0, stream>>>(ei, ew, nbrCnt, nbrNode, nbrW);
    k_match<<<eb4, 256, 0, stream>>>(ei, ew, nbrCnt, nbrNode, mCnt, mS, mD, mW, bitmap);
    k_deg<<<eb4, 256, 0, stream>>>(ei, ew, bitmap, deg);
    k_accum<<<32, 384, 0, stream>>>(x, h, deg, nbrCnt, nbrNode, nbrW, mCnt, mS, mD, mW,
                                    A1x, A2x, A1h, A2h);
    k_gemv<<<32, 256, 0, stream>>>(x, h, A1x, A2x, A1h, A2h, theta_x, theta_h, gacc);
    k_gates<<<1, 256, 0, stream>>>(c, gacc, bias_x, bias_h, w_c, b_gate, hbuf, cbuf);
    for (int t = 0; t < TT; ++t)
        k_step<<<32, 64, 0, stream>>>(t, x, w_ih, w_hh, b_ih, b_hh, w_out, b_out, hbuf, cbuf, obuf);
    k_final<<<1, 64, 0, stream>>>(obuf, b_out, out);
}